// Round 2
// baseline (1177.711 us; speedup 1.0000x reference)
//
#include <hip/hip_runtime.h>
#include <stdint.h>

typedef unsigned int uint;
typedef unsigned long long ull;

#define HW 3600
#define CDIM 256
#define KNN 64
#define M_REAL 7200
#define PADM 7232          // 7200 padded to multiple of 64 (113*64)
#define QPB 8              // topk queries per block (one per wave)

#define GRID_BLKS 512      // persistent grid: 2 blocks/CU x 256 CU, guaranteed
#define NTOPK 900
#define NINIT 904
#define NGEMM0 452
#define NSETUP 64
#define NLIGHT (NINIT + NGEMM0 + NSETUP)   // 1420
#define NGATHER 900        // 8 queries each
#define NGEMMT 452         // 64x64 tiles: 113 x 4
#define LDKP 264

using short8  = __attribute__((ext_vector_type(8))) short;
using floatx4 = __attribute__((ext_vector_type(4))) float;

__device__ inline unsigned short f2bf(float f) {   // RNE fp32 -> bf16 bits
    uint u = __float_as_uint(f);
    uint r = u + 0x7FFFu + ((u >> 16) & 1u);
    return (unsigned short)(r >> 16);
}
__device__ inline float bf2f(unsigned short b) {
    return __uint_as_float(((uint)b) << 16);
}

#define WAVE_LDS_FENCE() asm volatile("s_waitcnt lgkmcnt(0)" ::: "memory")

union MegaSmem {
    struct {
        float4 pts[HW];                  // 57600 B
        uint hist[QPB][256];             // 8192 B
        uint s_bin[QPB], s_want[QPB], s_cnt[QPB];
    } tk;
    struct { float tile[2][32][33]; } ih;
    struct { unsigned short As[64 * LDKP]; unsigned short Bs[64 * LDKP]; } ge; // 67584 B
};

// ---------------------------------------------------------------------------
// Device-scope grid barrier (generation-counted: robust to rocprof replay
// without memset as long as counter is a multiple of GRID_BLKS at entry).
// Co-residency guaranteed: LDS 67.6KB (2/CU) + launch_bounds(512,4) (VGPR<=128
// -> 16 waves/CU). All 512 blocks resident => no deadlock.
// ---------------------------------------------------------------------------
__device__ inline void gsync(uint* bar, int i) {
    __syncthreads();
    if (threadIdx.x == 0) {
        __threadfence();   // agent-scope release of this block's prior stores
        uint t = __hip_atomic_fetch_add(&bar[i], 1u, __ATOMIC_ACQ_REL,
                                        __HIP_MEMORY_SCOPE_AGENT);
        uint target = (t / GRID_BLKS + 1u) * GRID_BLKS;
        while (__hip_atomic_load(&bar[i], __ATOMIC_ACQUIRE,
                                 __HIP_MEMORY_SCOPE_AGENT) < target)
            __builtin_amdgcn_s_sleep(1);
    }
    __syncthreads();
}

// ---------------------------------------------------------------------------
// wave_select: threshold byte-bin from a 256-bin wave-private histogram.
// ---------------------------------------------------------------------------
__device__ inline void wave_select(uint* hist, uint* s_bin, uint* s_want,
                                   int lane, uint want) {
    uint h0 = hist[4 * lane + 0], h1 = hist[4 * lane + 1];
    uint h2 = hist[4 * lane + 2], h3 = hist[4 * lane + 3];
    hist[4 * lane + 0] = 0; hist[4 * lane + 1] = 0;
    hist[4 * lane + 2] = 0; hist[4 * lane + 3] = 0;
    uint c4 = h0 + h1 + h2 + h3;
    uint v = c4;
    #pragma unroll
    for (int off = 1; off < 64; off <<= 1) {
        uint o = __shfl_up(v, off, 64);
        if (lane >= off) v += o;
    }
    uint below = v - c4;
    if (below < want && want <= v) {
        uint b = 4 * lane, c = below;
        if (c + h0 < want) { c += h0; b = 4 * lane + 1;
            if (c + h1 < want) { c += h1; b = 4 * lane + 2;
                if (c + h2 < want) { c += h2; b = 4 * lane + 3; } } }
        *s_bin = b;
        *s_want = want - c;
    }
}

// ---------------------------------------------------------------------------
// topk body (verified in rounds 0/1). Leading __syncthreads protects LDS
// reuse between consecutive virtual blocks within a persistent block.
// ---------------------------------------------------------------------------
static __device__ void topk_body(MegaSmem& sm, int t,
                                 const float* __restrict__ points,
                                 int* __restrict__ idx_out) {
    const int wv = threadIdx.x >> 6;
    const int lane = threadIdx.x & 63;
    const int q = t * QPB + wv;
    const int n = (t * QPB) / HW;            // batch uniform per block
    const int i = q - n * HW;

    const float* __restrict__ px = points + (size_t)n * 3 * HW;
    const float* __restrict__ py = px + HW;
    const float* __restrict__ pz = py + HW;

    __syncthreads();                         // protect previous LDS users
    for (int j = threadIdx.x; j < HW; j += 512)
        sm.tk.pts[j] = make_float4(px[j], py[j], pz[j], 0.0f);
    sm.tk.hist[wv][4 * lane + 0] = 0; sm.tk.hist[wv][4 * lane + 1] = 0;
    sm.tk.hist[wv][4 * lane + 2] = 0; sm.tk.hist[wv][4 * lane + 3] = 0;
    if (lane == 0) sm.tk.s_cnt[wv] = 0;
    __syncthreads();                         // pts is block-shared

    float4 pq = sm.tk.pts[i];
    const float xi = pq.x, yi = pq.y, zi = pq.z;
    const float sqi = xi * xi + yi * yi + zi * zi;

    uint qp[29];
    #pragma unroll
    for (int s = 0; s < 57; ++s) {
        int j = (s << 6) + lane;
        uint q16 = 0xFFFFu;
        if (j < HW) {
            float4 p = sm.tk.pts[j];
            float d2 = fmaxf(sqi + (p.x * p.x + p.y * p.y + p.z * p.z)
                             - 2.0f * (xi * p.x + yi * p.y + zi * p.z), 0.0f);
            q16 = (uint)fminf(d2 * 1024.0f, 65535.0f);
        }
        if (s & 1) qp[s >> 1] |= q16 << 16; else qp[s >> 1] = q16;
    }
    #define Q16(s) ((qp[(s) >> 1] >> (((s) & 1) << 4)) & 0xFFFFu)

    #pragma unroll
    for (int s = 0; s < 57; ++s) {
        int j = (s << 6) + lane;
        if (j < HW) atomicAdd(&sm.tk.hist[wv][Q16(s) >> 8], 1u);
    }
    WAVE_LDS_FENCE();
    wave_select(&sm.tk.hist[wv][0], &sm.tk.s_bin[wv], &sm.tk.s_want[wv], lane, KNN);
    WAVE_LDS_FENCE();
    const uint qT8 = sm.tk.s_bin[wv];
    const uint want2 = sm.tk.s_want[wv];

    #pragma unroll
    for (int s = 0; s < 57; ++s) {
        int j = (s << 6) + lane;
        uint k = Q16(s);
        if (j < HW && (k >> 8) == qT8)
            atomicAdd(&sm.tk.hist[wv][k & 255u], 1u);
    }
    WAVE_LDS_FENCE();
    wave_select(&sm.tk.hist[wv][0], &sm.tk.s_bin[wv], &sm.tk.s_want[wv], lane, want2);
    WAVE_LDS_FENCE();
    const uint qT16 = (qT8 << 8) | sm.tk.s_bin[wv];
    const uint want3 = sm.tk.s_want[wv];

    #pragma unroll
    for (int s = 0; s < 57; ++s) {
        if (Q16(s) < qT16) {
            uint pos = atomicAdd(&sm.tk.s_cnt[wv], 1u);
            if (pos < KNN) idx_out[(size_t)q * KNN + pos] = (s << 6) + lane;
        }
    }

    ull cand[4] = {~0ULL, ~0ULL, ~0ULL, ~0ULL};
    int ncand = 0;
    #pragma unroll
    for (int s = 0; s < 57; ++s) {
        int j = (s << 6) + lane;
        if (j < HW && Q16(s) == qT16) {
            float4 p = sm.tk.pts[j];
            float d2 = fmaxf(sqi + (p.x * p.x + p.y * p.y + p.z * p.z)
                             - 2.0f * (xi * p.x + yi * p.y + zi * p.z), 0.0f);
            ull key = ((ull)__float_as_uint(d2) << 32) | (uint)j;
            if      (ncand == 0) cand[0] = key;
            else if (ncand == 1) cand[1] = key;
            else if (ncand == 2) cand[2] = key;
            else if (ncand == 3) cand[3] = key;
            ++ncand;
        }
    }
    const int base = KNN - (int)want3;
    if (__ballot(ncand > 4) == 0ULL) {
        for (int r = 0; r < (int)want3; ++r) {
            ull best = cand[0] < cand[1] ? cand[0] : cand[1];
            ull b23  = cand[2] < cand[3] ? cand[2] : cand[3];
            best = best < b23 ? best : b23;
            #pragma unroll
            for (int off = 1; off < 64; off <<= 1) {
                ull o = __shfl_xor(best, off, 64);
                if (o < best) best = o;
            }
            if (lane == 0) idx_out[(size_t)q * KNN + base + r] = (int)(uint)best;
            #pragma unroll
            for (int c = 0; c < 4; ++c)
                if (cand[c] == best) cand[c] = ~0ULL;
        }
    } else {
        ull used = 0ULL;
        for (int r = 0; r < (int)want3; ++r) {
            ull best = ~0ULL;
            #pragma unroll
            for (int s = 0; s < 57; ++s) {
                int j = (s << 6) + lane;
                if (j < HW && Q16(s) == qT16 && !((used >> s) & 1ULL)) {
                    float4 p = sm.tk.pts[j];
                    float d2 = fmaxf(sqi + (p.x * p.x + p.y * p.y + p.z * p.z)
                                     - 2.0f * (xi * p.x + yi * p.y + zi * p.z), 0.0f);
                    ull key = ((ull)__float_as_uint(d2) << 32) | (uint)j;
                    if (key < best) best = key;
                }
            }
            #pragma unroll
            for (int off = 1; off < 64; off <<= 1) {
                ull o = __shfl_xor(best, off, 64);
                if (o < best) best = o;
            }
            uint jw = (uint)best;
            if (lane == 0) idx_out[(size_t)q * KNN + base + r] = (int)jw;
            if ((int)(jw & 63u) == lane) used |= 1ULL << (jw >> 6);
        }
    }
    #undef Q16
}

// ---------------------------------------------------------------------------
// init_h body: h0 bf16 transpose into NHa left half + fp32 passthrough to out
// ---------------------------------------------------------------------------
static __device__ void init_body(MegaSmem& sm, int b,
                                 const float* __restrict__ cnn,
                                 unsigned short* __restrict__ NH,
                                 float* __restrict__ out) {
    const int n = b / 452;
    const int r = b - n * 452;
    const int hw0 = (r % 113) * 32;
    const int c0 = (r / 113) * 64 + ((threadIdx.x >> 8) << 5);
    const int t8 = threadIdx.x & 255;
    const int tx = t8 & 31;
    const int ty = t8 >> 5;
    __syncthreads();
    float (*tile)[33] = sm.ih.tile[threadIdx.x >> 8];
    const float* __restrict__ src = cnn + (size_t)n * CDIM * HW;
    #pragma unroll
    for (int rr = 0; rr < 4; ++rr) {
        int cc = ty + rr * 8;
        int hw = hw0 + tx;
        if (hw < HW) {
            float v = src[(size_t)(c0 + cc) * HW + hw];
            tile[cc][tx] = v;
            out[(size_t)n * (2 * CDIM * HW) + (size_t)(c0 + cc) * HW + hw] = v;
        }
    }
    __syncthreads();
    #pragma unroll
    for (int rr = 0; rr < 4; ++rr) {
        int hh = ty + rr * 8;
        int hw = hw0 + hh;
        if (hw < HW)
            NH[(size_t)(n * HW + hw) * 512 + c0 + tx] = f2bf(tile[tx][hh]);
    }
}

// ---------------------------------------------------------------------------
// fused iter-0 mlp GEMM body: reads fp32 cnn (transpose-stage) + fp32 mlp_w,
// no dependency on init_h/setup. Verified round 1.
// ---------------------------------------------------------------------------
static __device__ void gemm0_body(MegaSmem& sm, int g,
                                  const float* __restrict__ cnn,
                                  const float* __restrict__ mw,
                                  const float* __restrict__ mlp_bias,
                                  unsigned short* __restrict__ Tb) {
    const int m0 = (g % 113) * 64;
    const int n0 = (g / 113) * 64;
    const int tid = threadIdx.x;
    __syncthreads();
    const bool fast = (m0 + 64 <= HW) || (m0 >= HW && m0 + 64 <= M_REAL);
    if (fast) {
        const int nn = m0 >= HW;
        const float* __restrict__ base =
            cnn + (size_t)nn * CDIM * HW + (m0 - nn * HW);
        #pragma unroll
        for (int i = 0; i < 8; ++i) {
            int L = i * 512 + tid;
            int c = L >> 4, seg = L & 15;
            float4 v = *(const float4*)&base[(size_t)c * HW + seg * 4];
            sm.ge.As[(seg * 4 + 0) * LDKP + c] = f2bf(v.x);
            sm.ge.As[(seg * 4 + 1) * LDKP + c] = f2bf(v.y);
            sm.ge.As[(seg * 4 + 2) * LDKP + c] = f2bf(v.z);
            sm.ge.As[(seg * 4 + 3) * LDKP + c] = f2bf(v.w);
        }
    } else {
        #pragma unroll
        for (int i = 0; i < 8; ++i) {
            int L = i * 512 + tid;
            int c = L >> 4, seg = L & 15;
            #pragma unroll
            for (int k = 0; k < 4; ++k) {
                int m = m0 + seg * 4 + k;
                float v = 0.0f;
                if (m < M_REAL) {
                    int nn = m >= HW;
                    v = cnn[(size_t)nn * CDIM * HW + (size_t)c * HW + (m - nn * HW)];
                }
                sm.ge.As[(seg * 4 + k) * LDKP + c] = f2bf(v);
            }
        }
    }
    #pragma unroll
    for (int i = 0; i < 8; ++i) {
        int L = i * 512 + tid;
        int row = L >> 6, k4 = (L & 63) * 4;
        float4 v = *(const float4*)&mw[(size_t)(n0 + row) * CDIM + k4];
        uint2 p;
        p.x = (uint)f2bf(v.x) | ((uint)f2bf(v.y) << 16);
        p.y = (uint)f2bf(v.z) | ((uint)f2bf(v.w) << 16);
        *(uint2*)&sm.ge.Bs[row * LDKP + k4] = p;
    }
    __syncthreads();

    const int w = tid >> 6;
    const int lane = tid & 63;
    const int l15 = lane & 15;
    const int qd = lane >> 4;
    const int wm = (w & 1) * 32;
    const int wn = (w >> 1) * 16;
    floatx4 acc0 = (floatx4){0.f, 0.f, 0.f, 0.f};
    floatx4 acc1 = (floatx4){0.f, 0.f, 0.f, 0.f};
    #pragma unroll
    for (int ks = 0; ks < 256; ks += 32) {
        short8 a0 = *(const short8*)&sm.ge.As[(wm + l15) * LDKP + ks + qd * 8];
        short8 a1 = *(const short8*)&sm.ge.As[(wm + 16 + l15) * LDKP + ks + qd * 8];
        short8 b0 = *(const short8*)&sm.ge.Bs[(wn + l15) * LDKP + ks + qd * 8];
        acc0 = __builtin_amdgcn_mfma_f32_16x16x32_bf16(a0, b0, acc0, 0, 0, 0);
        acc1 = __builtin_amdgcn_mfma_f32_16x16x32_bf16(a1, b0, acc1, 0, 0, 0);
    }
    const int col = n0 + wn + l15;
    const float bv = mlp_bias[col];
    #pragma unroll
    for (int im = 0; im < 2; ++im) {
        int mb = m0 + wm + im * 16 + qd * 4;
        floatx4 a = im ? acc1 : acc0;
        #pragma unroll
        for (int r = 0; r < 4; ++r)
            Tb[(size_t)(mb + r) * CDIM + col] = f2bf(fmaxf(a[r] + bv, 0.0f));
    }
}

static __device__ void setup_body(int s, const float* __restrict__ mw,
                                  const float* __restrict__ rw,
                                  unsigned short* __restrict__ mo,
                                  unsigned short* __restrict__ ro) {
    int i0 = s * 2048 + threadIdx.x * 4;
    float4 v = *(const float4*)&rw[i0];
    uint2 p;
    p.x = (uint)f2bf(v.x) | ((uint)f2bf(v.y) << 16);
    p.y = (uint)f2bf(v.z) | ((uint)f2bf(v.w) << 16);
    *(uint2*)&ro[i0] = p;
    if (i0 < 65536) {
        float4 m = *(const float4*)&mw[i0];
        p.x = (uint)f2bf(m.x) | ((uint)f2bf(m.y) << 16);
        p.y = (uint)f2bf(m.z) | ((uint)f2bf(m.w) << 16);
        *(uint2*)&mo[i0] = p;
    }
}

// ---------------------------------------------------------------------------
// gather body: 8 queries per virtual block (one/wave), no LDS.
// ---------------------------------------------------------------------------
static __device__ void gather_body(int g, const unsigned short* __restrict__ T,
                                   const int* __restrict__ idx,
                                   unsigned short* __restrict__ NH) {
    const int q = g * 8 + (threadIdx.x >> 6);
    const int lane = threadIdx.x & 63;
    const int n = q / HW;
    const int half = lane >> 5;
    const int c8 = (lane & 31) * 8;

    const int nbrL = idx[(size_t)q * KNN + lane];
    float acc[8] = {0, 0, 0, 0, 0, 0, 0, 0};
    #pragma unroll 4
    for (int it = 0; it < 32; ++it) {
        int k = 2 * it + half;
        int j = __shfl(nbrL, k, 64);
        j = min(max(j, 0), HW - 1);
        int r = n * HW + j;
        uint4 v = *(const uint4*)&T[(size_t)r * CDIM + c8];
        acc[0] += bf2f((unsigned short)(v.x & 0xFFFFu));
        acc[1] += bf2f((unsigned short)(v.x >> 16));
        acc[2] += bf2f((unsigned short)(v.y & 0xFFFFu));
        acc[3] += bf2f((unsigned short)(v.y >> 16));
        acc[4] += bf2f((unsigned short)(v.z & 0xFFFFu));
        acc[5] += bf2f((unsigned short)(v.z >> 16));
        acc[6] += bf2f((unsigned short)(v.w & 0xFFFFu));
        acc[7] += bf2f((unsigned short)(v.w >> 16));
    }
    #pragma unroll
    for (int c = 0; c < 8; ++c) acc[c] += __shfl_xor(acc[c], 32, 64);
    if (half == 0) {
        uint4 o;
        o.x = (uint)f2bf(acc[0] * (1.0f / KNN)) | ((uint)f2bf(acc[1] * (1.0f / KNN)) << 16);
        o.y = (uint)f2bf(acc[2] * (1.0f / KNN)) | ((uint)f2bf(acc[3] * (1.0f / KNN)) << 16);
        o.z = (uint)f2bf(acc[4] * (1.0f / KNN)) | ((uint)f2bf(acc[5] * (1.0f / KNN)) << 16);
        o.w = (uint)f2bf(acc[6] * (1.0f / KNN)) | ((uint)f2bf(acc[7] * (1.0f / KNN)) << 16);
        *(uint4*)&NH[(size_t)q * 512 + CDIM + c8] = o;
    }
}

// ---------------------------------------------------------------------------
// bf16 MFMA GEMM body, 512 threads / 8 waves, 64x64 tile, BK=256 chunks.
// Threads 0-255 stage As, 256-511 stage Bs. Wave tile 32x16 (2x1 frags).
// mode 0: bf16 store (mb<M_REAL guarded: keeps NHa padding rows clean for
// the barrier counters); mode 1: fused fp32 transpose-store into out.
// ---------------------------------------------------------------------------
static __device__ void gemm_body(MegaSmem& sm, int v,
    const unsigned short* __restrict__ A, int lda,
    const unsigned short* __restrict__ W, int ldw,
    const float* __restrict__ bias,
    unsigned short* __restrict__ Cb, int ldc,
    float* __restrict__ outp, int mode, int Kk) {
    const int m0 = (v % 113) * 64;
    const int n0 = (v / 113) * 64;
    const int tid = threadIdx.x;
    const int lane = tid & 63;
    const int w = tid >> 6;
    const int wm = (w & 1) * 32;
    const int wn = (w >> 1) * 16;
    const int l15 = lane & 15;
    const int qd = lane >> 4;

    const int tt = tid & 255;
    const int mat = tid >> 8;                 // 0: A, 1: B
    const int srow = tt >> 5;                 // 0..7
    const int scol = (tt & 31) * 8;           // 16B chunks across 256 cols
    const unsigned short* __restrict__ S = mat ? W : A;
    const int lds_ = mat ? ldw : lda;
    unsigned short* dst = mat ? sm.ge.Bs : sm.ge.As;
    const int rbase = mat ? n0 : m0;

    floatx4 acc0 = (floatx4){0.f, 0.f, 0.f, 0.f};
    floatx4 acc1 = (floatx4){0.f, 0.f, 0.f, 0.f};

    for (int k0 = 0; k0 < Kk; k0 += 256) {
        __syncthreads();
        #pragma unroll
        for (int r8 = 0; r8 < 8; ++r8) {
            int row = r8 * 8 + srow;
            *(float4*)&dst[row * LDKP + scol] =
                *(const float4*)&S[(size_t)(rbase + row) * lds_ + k0 + scol];
        }
        __syncthreads();
        #pragma unroll
        for (int ks = 0; ks < 256; ks += 32) {
            short8 a0 = *(const short8*)&sm.ge.As[(wm + l15) * LDKP + ks + qd * 8];
            short8 a1 = *(const short8*)&sm.ge.As[(wm + 16 + l15) * LDKP + ks + qd * 8];
            short8 b0 = *(const short8*)&sm.ge.Bs[(wn + l15) * LDKP + ks + qd * 8];
            acc0 = __builtin_amdgcn_mfma_f32_16x16x32_bf16(a0, b0, acc0, 0, 0, 0);
            acc1 = __builtin_amdgcn_mfma_f32_16x16x32_bf16(a1, b0, acc1, 0, 0, 0);
        }
    }

    const int col = n0 + wn + l15;
    const float bv = bias[col];
    #pragma unroll
    for (int im = 0; im < 2; ++im) {
        int mb = m0 + wm + im * 16 + qd * 4;
        floatx4 a = im ? acc1 : acc0;
        if (mode == 0) {
            if (mb < M_REAL) {
                #pragma unroll
                for (int r = 0; r < 4; ++r)
                    Cb[(size_t)(mb + r) * ldc + col] =
                        f2bf(fmaxf(a[r] + bv, 0.0f));
            }
        } else if (mb < M_REAL) {
            int nb = mb / HW;
            int hw = mb - nb * HW;
            float4 o;
            o.x = fmaxf(a[0] + bv, 0.0f);
            o.y = fmaxf(a[1] + bv, 0.0f);
            o.z = fmaxf(a[2] + bv, 0.0f);
            o.w = fmaxf(a[3] + bv, 0.0f);
            *(float4*)&outp[(size_t)nb * (2 * CDIM * HW)
                            + (size_t)(CDIM + col) * HW + hw] = o;
        }
    }
}

// ---------------------------------------------------------------------------
// Persistent pipeline: one launch for the whole network. 512 blocks x 512
// threads, 8 grid barriers replace 9 kernel boundaries.
// ---------------------------------------------------------------------------
__global__ __launch_bounds__(512, 4) void pipeline(
    const float* __restrict__ points, int* __restrict__ idx,
    const float* __restrict__ cnn,
    unsigned short* __restrict__ NHa, unsigned short* __restrict__ NHb,
    unsigned short* __restrict__ Tb, float* __restrict__ out,
    const float* __restrict__ mw, const float* __restrict__ mb_,
    const float* __restrict__ rw, const float* __restrict__ rb_,
    unsigned short* __restrict__ mo, unsigned short* __restrict__ ro,
    uint* __restrict__ bar) {
    __shared__ MegaSmem sm;
    const int blk = blockIdx.x;

    // ---- phase 0: topk + init_h + gemm0 + setup ----
    for (int t = blk; t < NTOPK; t += GRID_BLKS)
        topk_body(sm, t, points, idx);
    // light work, assigned inversely to topk load: blocks 0-387 carry 2 topk
    // vbs -> 1 light vb; blocks 388-511 carry 1 topk vb -> ~8 light vbs.
    if (blk < 388) {
        init_body(sm, blk, cnn, NHa, out);   // l = blk < 904: always init
    } else {
        for (int l = blk; l < NLIGHT; l += 124) {
            if (l < NINIT)              init_body(sm, l, cnn, NHa, out);
            else if (l < NINIT + NGEMM0) gemm0_body(sm, l - NINIT, cnn, mw, mb_, Tb);
            else                        setup_body(l - NINIT - NGEMM0, mw, rw, mo, ro);
        }
    }
    gsync(bar, 0);

    // ---- it 0 ----
    for (int g = blk; g < NGATHER; g += GRID_BLKS) gather_body(g, Tb, idx, NHa);
    gsync(bar, 1);
    if (blk < NGEMMT) gemm_body(sm, blk, NHa, 512, ro, 512, rb_, NHb, 512, nullptr, 0, 512);
    gsync(bar, 2);
    if (blk < NGEMMT) gemm_body(sm, blk, NHb, 512, mo, CDIM, mb_, Tb, CDIM, nullptr, 0, CDIM);
    gsync(bar, 3);

    // ---- it 1 ----
    for (int g = blk; g < NGATHER; g += GRID_BLKS) gather_body(g, Tb, idx, NHb);
    gsync(bar, 4);
    if (blk < NGEMMT) gemm_body(sm, blk, NHb, 512, ro, 512, rb_, NHa, 512, nullptr, 0, 512);
    gsync(bar, 5);
    if (blk < NGEMMT) gemm_body(sm, blk, NHa, 512, mo, CDIM, mb_, Tb, CDIM, nullptr, 0, CDIM);
    gsync(bar, 6);

    // ---- it 2 ----
    for (int g = blk; g < NGATHER; g += GRID_BLKS) gather_body(g, Tb, idx, NHa);
    gsync(bar, 7);
    if (blk < NGEMMT) gemm_body(sm, blk, NHa, 512, ro, 512, rb_, nullptr, 0, out, 1, 512);
}

extern "C" void kernel_launch(void* const* d_in, const int* in_sizes, int n_in,
                              void* d_out, int out_size, void* d_ws, size_t ws_size,
                              hipStream_t stream) {
    const float* cnn   = (const float*)d_in[0];
    const float* pts   = (const float*)d_in[1];
    const float* mlp_w = (const float*)d_in[2];
    const float* mlp_b = (const float*)d_in[3];
    const float* rnn_w = (const float*)d_in[4];
    const float* rnn_b = (const float*)d_in[5];
    float* out = (float*)d_out;

    // workspace (unchanged footprint):
    // NHa(7232x512 u16) | NHb(7232x512 u16) | Tb(7232x256 u16)
    // | mlpw_b(65536 u16) | rnnw_b(131072 u16) | idx(7200x64 int)
    // barrier counters live in NHa's never-written padding rows (>= 7200).
    unsigned short* NHa    = (unsigned short*)d_ws;
    unsigned short* NHb    = NHa + (size_t)PADM * 512;
    unsigned short* Tb     = NHb + (size_t)PADM * 512;
    unsigned short* mlpw_b = Tb + (size_t)PADM * CDIM;
    unsigned short* rnnw_b = mlpw_b + 65536;
    int*            idx    = (int*)(rnnw_b + 131072);
    uint*           bar    = (uint*)(NHa + (size_t)M_REAL * 512);

    hipMemsetAsync(bar, 0, 64, stream);
    pipeline<<<GRID_BLKS, 512, 0, stream>>>(
        pts, idx, cnn, NHa, NHb, Tb, out,
        mlp_w, mlp_b, rnn_w, rnn_b, mlpw_b, rnnw_b, bar);
}

// Round 3
// 853.975 us; speedup vs baseline: 1.3791x; 1.3791x over previous
//
#include <hip/hip_runtime.h>
#include <stdint.h>

typedef unsigned int uint;
typedef unsigned long long ull;

#define HW 3600
#define CDIM 256
#define KNN 64
#define M_REAL 7200
#define PADM 7232          // 7200 padded to multiple of 64 (113*64)
#define QPB 8              // topk queries per block (one per wave)

#define TKB 900            // topk blocks
#define IHB 904            // init_h blocks (2 c-tiles each)
#define SUB 64             // setup blocks

#define GRID_B 512         // persistent tail grid: 2 blocks/CU guaranteed
#define NGATHER 900        // 8 queries each
#define NGEMMT 452         // 64x64 tiles: 113 x 4
#define LDKP 264

using short8  = __attribute__((ext_vector_type(8))) short;
using floatx4 = __attribute__((ext_vector_type(4))) float;

__device__ inline unsigned short f2bf(float f) {   // RNE fp32 -> bf16 bits
    uint u = __float_as_uint(f);
    uint r = u + 0x7FFFu + ((u >> 16) & 1u);
    return (unsigned short)(r >> 16);
}
__device__ inline float bf2f(unsigned short b) {
    return __uint_as_float(((uint)b) << 16);
}

#define WAVE_LDS_FENCE() asm volatile("s_waitcnt lgkmcnt(0)" ::: "memory")

// ---------------------------------------------------------------------------
// wave_select: threshold byte-bin from a 256-bin wave-private histogram.
// ---------------------------------------------------------------------------
__device__ inline void wave_select(uint* hist, uint* s_bin, uint* s_want,
                                   int lane, uint want) {
    uint h0 = hist[4 * lane + 0], h1 = hist[4 * lane + 1];
    uint h2 = hist[4 * lane + 2], h3 = hist[4 * lane + 3];
    hist[4 * lane + 0] = 0; hist[4 * lane + 1] = 0;
    hist[4 * lane + 2] = 0; hist[4 * lane + 3] = 0;
    uint c4 = h0 + h1 + h2 + h3;
    uint v = c4;
    #pragma unroll
    for (int off = 1; off < 64; off <<= 1) {
        uint o = __shfl_up(v, off, 64);
        if (lane >= off) v += o;
    }
    uint below = v - c4;
    if (below < want && want <= v) {
        uint b = 4 * lane, c = below;
        if (c + h0 < want) { c += h0; b = 4 * lane + 1;
            if (c + h1 < want) { c += h1; b = 4 * lane + 2;
                if (c + h2 < want) { c += h2; b = 4 * lane + 3; } } }
        *s_bin = b;
        *s_want = want - c;
    }
}

// ---------------------------------------------------------------------------
// Mega-kernel (round-0 structure, verbatim roles; 62 µs measured, VGPR 128).
// Plain launch_bounds(512): NO min-waves cap — topk needs ~128 arch VGPRs
// (round 2 proved capping to 128 unified splits 64/64 and spills 700 MB).
// Also zeroes the tail kernel's 8 barrier words (block TKB, replaces memset).
// ---------------------------------------------------------------------------
union MegaSmem {
    struct {
        float4 pts[HW];                  // 57600 B
        uint hist[QPB][256];             // 8192 B
        uint s_bin[QPB], s_want[QPB], s_cnt[QPB];
    } tk;
    struct { float tile[2][32][33]; } ih;
};

__global__ __launch_bounds__(512) void mega_kernel(
    const float* __restrict__ points, int* __restrict__ idx_out,
    const float* __restrict__ cnn, unsigned short* __restrict__ NH,
    float* __restrict__ out,
    const float* __restrict__ mw, const float* __restrict__ rw,
    unsigned short* __restrict__ mo, unsigned short* __restrict__ ro,
    uint* __restrict__ bar) {
    __shared__ MegaSmem sm;
    const int blk = blockIdx.x;

    if (blk >= TKB + IHB) {
        // ---- setup role ----
        int i0 = (blk - TKB - IHB) * 2048 + threadIdx.x * 4;
        float4 v = *(const float4*)&rw[i0];
        uint2 p;
        p.x = (uint)f2bf(v.x) | ((uint)f2bf(v.y) << 16);
        p.y = (uint)f2bf(v.z) | ((uint)f2bf(v.w) << 16);
        *(uint2*)&ro[i0] = p;
        if (i0 < 65536) {
            float4 m = *(const float4*)&mw[i0];
            p.x = (uint)f2bf(m.x) | ((uint)f2bf(m.y) << 16);
            p.y = (uint)f2bf(m.z) | ((uint)f2bf(m.w) << 16);
            *(uint2*)&mo[i0] = p;
        }
        return;
    }

    if (blk >= TKB) {
        // ---- init_h role: two 32x32 c-tiles per block ----
        if (blk == TKB && threadIdx.x < 8) bar[threadIdx.x] = 0;  // tail barriers
        const int b = blk - TKB;             // 0..903
        const int n = b / 452;
        const int r = b - n * 452;
        const int hw0 = (r % 113) * 32;
        const int c0 = (r / 113) * 64 + ((threadIdx.x >> 8) << 5);
        const int t8 = threadIdx.x & 255;
        const int tx = t8 & 31;
        const int ty = t8 >> 5;              // 0..7
        float (*tile)[33] = sm.ih.tile[threadIdx.x >> 8];
        const float* __restrict__ src = cnn + (size_t)n * CDIM * HW;
        #pragma unroll
        for (int rr = 0; rr < 4; ++rr) {
            int cc = ty + rr * 8;
            int hw = hw0 + tx;
            if (hw < HW) {
                float v = src[(size_t)(c0 + cc) * HW + hw];
                tile[cc][tx] = v;
                out[(size_t)n * (2 * CDIM * HW) + (size_t)(c0 + cc) * HW + hw] = v;
            }
        }
        __syncthreads();
        #pragma unroll
        for (int rr = 0; rr < 4; ++rr) {
            int hh = ty + rr * 8;
            int hw = hw0 + hh;
            if (hw < HW)
                NH[(size_t)(n * HW + hw) * 512 + c0 + tx] = f2bf(tile[tx][hh]);
        }
        return;
    }

    // ---- topk role ----
    const int wv = threadIdx.x >> 6;
    const int lane = threadIdx.x & 63;
    const int q = blk * QPB + wv;
    const int n = (blk * QPB) / HW;          // batch uniform per block (450 | 8)
    const int i = q - n * HW;

    const float* __restrict__ px = points + (size_t)n * 3 * HW;
    const float* __restrict__ py = px + HW;
    const float* __restrict__ pz = py + HW;

    for (int j = threadIdx.x; j < HW; j += 512)
        sm.tk.pts[j] = make_float4(px[j], py[j], pz[j], 0.0f);
    sm.tk.hist[wv][4 * lane + 0] = 0; sm.tk.hist[wv][4 * lane + 1] = 0;
    sm.tk.hist[wv][4 * lane + 2] = 0; sm.tk.hist[wv][4 * lane + 3] = 0;
    if (lane == 0) sm.tk.s_cnt[wv] = 0;
    __syncthreads();          // the ONLY block barrier: pts is block-shared

    float4 pq = sm.tk.pts[i];
    const float xi = pq.x, yi = pq.y, zi = pq.z;
    const float sqi = xi * xi + yi * yi + zi * zi;

    uint qp[29];
    #pragma unroll
    for (int s = 0; s < 57; ++s) {
        int j = (s << 6) + lane;
        uint q16 = 0xFFFFu;                  // OOB sentinel (strip 56 only)
        if (j < HW) {
            float4 p = sm.tk.pts[j];
            float d2 = fmaxf(sqi + (p.x * p.x + p.y * p.y + p.z * p.z)
                             - 2.0f * (xi * p.x + yi * p.y + zi * p.z), 0.0f);
            q16 = (uint)fminf(d2 * 1024.0f, 65535.0f);
        }
        if (s & 1) qp[s >> 1] |= q16 << 16; else qp[s >> 1] = q16;
    }
    #define Q16(s) ((qp[(s) >> 1] >> (((s) & 1) << 4)) & 0xFFFFu)

    #pragma unroll
    for (int s = 0; s < 57; ++s) {
        int j = (s << 6) + lane;
        if (j < HW) atomicAdd(&sm.tk.hist[wv][Q16(s) >> 8], 1u);
    }
    WAVE_LDS_FENCE();
    wave_select(&sm.tk.hist[wv][0], &sm.tk.s_bin[wv], &sm.tk.s_want[wv], lane, KNN);
    WAVE_LDS_FENCE();
    const uint qT8 = sm.tk.s_bin[wv];
    const uint want2 = sm.tk.s_want[wv];

    #pragma unroll
    for (int s = 0; s < 57; ++s) {
        int j = (s << 6) + lane;
        uint k = Q16(s);
        if (j < HW && (k >> 8) == qT8)
            atomicAdd(&sm.tk.hist[wv][k & 255u], 1u);
    }
    WAVE_LDS_FENCE();
    wave_select(&sm.tk.hist[wv][0], &sm.tk.s_bin[wv], &sm.tk.s_want[wv], lane, want2);
    WAVE_LDS_FENCE();
    const uint qT16 = (qT8 << 8) | sm.tk.s_bin[wv];
    const uint want3 = sm.tk.s_want[wv];

    #pragma unroll
    for (int s = 0; s < 57; ++s) {
        if (Q16(s) < qT16) {
            uint pos = atomicAdd(&sm.tk.s_cnt[wv], 1u);
            if (pos < KNN) idx_out[(size_t)q * KNN + pos] = (s << 6) + lane;
        }
    }

    ull cand[4] = {~0ULL, ~0ULL, ~0ULL, ~0ULL};
    int ncand = 0;
    #pragma unroll
    for (int s = 0; s < 57; ++s) {
        int j = (s << 6) + lane;
        if (j < HW && Q16(s) == qT16) {
            float4 p = sm.tk.pts[j];
            float d2 = fmaxf(sqi + (p.x * p.x + p.y * p.y + p.z * p.z)
                             - 2.0f * (xi * p.x + yi * p.y + zi * p.z), 0.0f);
            ull key = ((ull)__float_as_uint(d2) << 32) | (uint)j;
            if      (ncand == 0) cand[0] = key;
            else if (ncand == 1) cand[1] = key;
            else if (ncand == 2) cand[2] = key;
            else if (ncand == 3) cand[3] = key;
            ++ncand;
        }
    }
    const int base = KNN - (int)want3;
    if (__ballot(ncand > 4) == 0ULL) {
        for (int r = 0; r < (int)want3; ++r) {
            ull best = cand[0] < cand[1] ? cand[0] : cand[1];
            ull b23  = cand[2] < cand[3] ? cand[2] : cand[3];
            best = best < b23 ? best : b23;
            #pragma unroll
            for (int off = 1; off < 64; off <<= 1) {
                ull o = __shfl_xor(best, off, 64);
                if (o < best) best = o;
            }
            if (lane == 0) idx_out[(size_t)q * KNN + base + r] = (int)(uint)best;
            #pragma unroll
            for (int c = 0; c < 4; ++c)
                if (cand[c] == best) cand[c] = ~0ULL;
        }
    } else {
        ull used = 0ULL;
        for (int r = 0; r < (int)want3; ++r) {
            ull best = ~0ULL;
            #pragma unroll
            for (int s = 0; s < 57; ++s) {
                int j = (s << 6) + lane;
                if (j < HW && Q16(s) == qT16 && !((used >> s) & 1ULL)) {
                    float4 p = sm.tk.pts[j];
                    float d2 = fmaxf(sqi + (p.x * p.x + p.y * p.y + p.z * p.z)
                                     - 2.0f * (xi * p.x + yi * p.y + zi * p.z), 0.0f);
                    ull key = ((ull)__float_as_uint(d2) << 32) | (uint)j;
                    if (key < best) best = key;
                }
            }
            #pragma unroll
            for (int off = 1; off < 64; off <<= 1) {
                ull o = __shfl_xor(best, off, 64);
                if (o < best) best = o;
            }
            uint jw = (uint)best;
            if (lane == 0) idx_out[(size_t)q * KNN + base + r] = (int)jw;
            if ((int)(jw & 63u) == lane) used |= 1ULL << (jw >> 6);
        }
    }
    #undef Q16
}

// ---------------------------------------------------------------------------
// Persistent tail: gather/gemm bodies only (low register pressure, so the
// (512,4) co-residency cap cannot spill). 2 blocks/CU guaranteed:
// LDS 67584 <= 80K, VGPR capped 128 -> 16 waves/CU.
// ---------------------------------------------------------------------------
struct GeSmem { unsigned short As[64 * LDKP]; unsigned short Bs[64 * LDKP]; };

__device__ inline void gsync(uint* bar, int i) {
    __syncthreads();
    if (threadIdx.x == 0) {
        __threadfence();   // agent-scope release of this block's prior stores
        uint t = __hip_atomic_fetch_add(&bar[i], 1u, __ATOMIC_ACQ_REL,
                                        __HIP_MEMORY_SCOPE_AGENT);
        uint target = (t / GRID_B + 1u) * GRID_B;
        while (__hip_atomic_load(&bar[i], __ATOMIC_ACQUIRE,
                                 __HIP_MEMORY_SCOPE_AGENT) < target)
            __builtin_amdgcn_s_sleep(1);
    }
    __syncthreads();
}

// gather body: 8 queries per virtual block (one/wave), no LDS.
static __device__ void gather_body(int g, const unsigned short* __restrict__ T,
                                   const int* __restrict__ idx,
                                   unsigned short* __restrict__ NH) {
    const int q = g * 8 + (threadIdx.x >> 6);
    const int lane = threadIdx.x & 63;
    const int n = q / HW;
    const int half = lane >> 5;
    const int c8 = (lane & 31) * 8;

    const int nbrL = idx[(size_t)q * KNN + lane];
    float acc[8] = {0, 0, 0, 0, 0, 0, 0, 0};
    #pragma unroll 4
    for (int it = 0; it < 32; ++it) {
        int k = 2 * it + half;
        int j = __shfl(nbrL, k, 64);
        j = min(max(j, 0), HW - 1);
        int r = n * HW + j;
        uint4 v = *(const uint4*)&T[(size_t)r * CDIM + c8];
        acc[0] += bf2f((unsigned short)(v.x & 0xFFFFu));
        acc[1] += bf2f((unsigned short)(v.x >> 16));
        acc[2] += bf2f((unsigned short)(v.y & 0xFFFFu));
        acc[3] += bf2f((unsigned short)(v.y >> 16));
        acc[4] += bf2f((unsigned short)(v.z & 0xFFFFu));
        acc[5] += bf2f((unsigned short)(v.z >> 16));
        acc[6] += bf2f((unsigned short)(v.w & 0xFFFFu));
        acc[7] += bf2f((unsigned short)(v.w >> 16));
    }
    #pragma unroll
    for (int c = 0; c < 8; ++c) acc[c] += __shfl_xor(acc[c], 32, 64);
    if (half == 0) {
        uint4 o;
        o.x = (uint)f2bf(acc[0] * (1.0f / KNN)) | ((uint)f2bf(acc[1] * (1.0f / KNN)) << 16);
        o.y = (uint)f2bf(acc[2] * (1.0f / KNN)) | ((uint)f2bf(acc[3] * (1.0f / KNN)) << 16);
        o.z = (uint)f2bf(acc[4] * (1.0f / KNN)) | ((uint)f2bf(acc[5] * (1.0f / KNN)) << 16);
        o.w = (uint)f2bf(acc[6] * (1.0f / KNN)) | ((uint)f2bf(acc[7] * (1.0f / KNN)) << 16);
        *(uint4*)&NH[(size_t)q * 512 + CDIM + c8] = o;
    }
}

// bf16 MFMA GEMM body, 512 threads / 8 waves, 64x64 tile, BK=256 chunks.
// Threads 0-255 stage As, 256-511 stage Bs. Wave tile 32x16 (2x1 frags).
// All stores guarded mb<M_REAL: keeps NHa/NHb padding rows (incl. barrier
// words) clean. Garbage padding rows of A only affect discarded C rows.
static __device__ void gemm_body(GeSmem& sm, int v,
    const unsigned short* __restrict__ A, int lda,
    const unsigned short* __restrict__ W, int ldw,
    const float* __restrict__ bias,
    unsigned short* __restrict__ Cb, int ldc,
    float* __restrict__ outp, int mode, int Kk) {
    const int m0 = (v % 113) * 64;
    const int n0 = (v / 113) * 64;
    const int tid = threadIdx.x;
    const int lane = tid & 63;
    const int w = tid >> 6;
    const int wm = (w & 1) * 32;
    const int wn = (w >> 1) * 16;
    const int l15 = lane & 15;
    const int qd = lane >> 4;

    const int tt = tid & 255;
    const int mat = tid >> 8;                 // 0: A, 1: B
    const int srow = tt >> 5;                 // 0..7
    const int scol = (tt & 31) * 8;           // 16B chunks across 256 cols
    const unsigned short* __restrict__ S = mat ? W : A;
    const int lds_ = mat ? ldw : lda;
    unsigned short* dst = mat ? sm.Bs : sm.As;
    const int rbase = mat ? n0 : m0;

    floatx4 acc0 = (floatx4){0.f, 0.f, 0.f, 0.f};
    floatx4 acc1 = (floatx4){0.f, 0.f, 0.f, 0.f};

    for (int k0 = 0; k0 < Kk; k0 += 256) {
        __syncthreads();
        #pragma unroll
        for (int r8 = 0; r8 < 8; ++r8) {
            int row = r8 * 8 + srow;
            *(float4*)&dst[row * LDKP + scol] =
                *(const float4*)&S[(size_t)(rbase + row) * lds_ + k0 + scol];
        }
        __syncthreads();
        #pragma unroll
        for (int ks = 0; ks < 256; ks += 32) {
            short8 a0 = *(const short8*)&sm.As[(wm + l15) * LDKP + ks + qd * 8];
            short8 a1 = *(const short8*)&sm.As[(wm + 16 + l15) * LDKP + ks + qd * 8];
            short8 b0 = *(const short8*)&sm.Bs[(wn + l15) * LDKP + ks + qd * 8];
            acc0 = __builtin_amdgcn_mfma_f32_16x16x32_bf16(a0, b0, acc0, 0, 0, 0);
            acc1 = __builtin_amdgcn_mfma_f32_16x16x32_bf16(a1, b0, acc1, 0, 0, 0);
        }
    }

    const int col = n0 + wn + l15;
    const float bv = bias[col];
    #pragma unroll
    for (int im = 0; im < 2; ++im) {
        int mb = m0 + wm + im * 16 + qd * 4;
        floatx4 a = im ? acc1 : acc0;
        if (mb < M_REAL) {
            if (mode == 0) {
                #pragma unroll
                for (int r = 0; r < 4; ++r)
                    Cb[(size_t)(mb + r) * ldc + col] =
                        f2bf(fmaxf(a[r] + bv, 0.0f));
            } else {
                int nb = mb / HW;
                int hw = mb - nb * HW;
                float4 o;
                o.x = fmaxf(a[0] + bv, 0.0f);
                o.y = fmaxf(a[1] + bv, 0.0f);
                o.z = fmaxf(a[2] + bv, 0.0f);
                o.w = fmaxf(a[3] + bv, 0.0f);
                *(float4*)&outp[(size_t)nb * (2 * CDIM * HW)
                                + (size_t)(CDIM + col) * HW + hw] = o;
            }
        }
    }
}

__global__ __launch_bounds__(512, 4) void tail_pipeline(
    unsigned short* __restrict__ NHa, unsigned short* __restrict__ NHb,
    unsigned short* __restrict__ Tb, const int* __restrict__ idx,
    float* __restrict__ out,
    const unsigned short* __restrict__ mo, const unsigned short* __restrict__ ro,
    const float* __restrict__ mb_, const float* __restrict__ rb_,
    uint* __restrict__ bar) {
    __shared__ GeSmem sm;
    const int blk = blockIdx.x;

    // ---- it 0 ----
    if (blk < NGEMMT) gemm_body(sm, blk, NHa, 512, mo, CDIM, mb_, Tb, CDIM, nullptr, 0, CDIM);
    gsync(bar, 0);
    for (int g = blk; g < NGATHER; g += GRID_B) gather_body(g, Tb, idx, NHa);
    gsync(bar, 1);
    if (blk < NGEMMT) gemm_body(sm, blk, NHa, 512, ro, 512, rb_, NHb, 512, nullptr, 0, 512);
    gsync(bar, 2);

    // ---- it 1 ----
    if (blk < NGEMMT) gemm_body(sm, blk, NHb, 512, mo, CDIM, mb_, Tb, CDIM, nullptr, 0, CDIM);
    gsync(bar, 3);
    for (int g = blk; g < NGATHER; g += GRID_B) gather_body(g, Tb, idx, NHb);
    gsync(bar, 4);
    if (blk < NGEMMT) gemm_body(sm, blk, NHb, 512, ro, 512, rb_, NHa, 512, nullptr, 0, 512);
    gsync(bar, 5);

    // ---- it 2 ----
    if (blk < NGEMMT) gemm_body(sm, blk, NHa, 512, mo, CDIM, mb_, Tb, CDIM, nullptr, 0, CDIM);
    gsync(bar, 6);
    for (int g = blk; g < NGATHER; g += GRID_B) gather_body(g, Tb, idx, NHa);
    gsync(bar, 7);
    if (blk < NGEMMT) gemm_body(sm, blk, NHa, 512, ro, 512, rb_, nullptr, 0, out, 1, 512);
}

extern "C" void kernel_launch(void* const* d_in, const int* in_sizes, int n_in,
                              void* d_out, int out_size, void* d_ws, size_t ws_size,
                              hipStream_t stream) {
    const float* cnn   = (const float*)d_in[0];
    const float* pts   = (const float*)d_in[1];
    const float* mlp_w = (const float*)d_in[2];
    const float* mlp_b = (const float*)d_in[3];
    const float* rnn_w = (const float*)d_in[4];
    const float* rnn_b = (const float*)d_in[5];
    float* out = (float*)d_out;

    // workspace (unchanged footprint):
    // NHa(7232x512 u16) | NHb(7232x512 u16) | Tb(7232x256 u16)
    // | mlpw_b(65536 u16) | rnnw_b(131072 u16) | idx(7200x64 int)
    // barrier counters live in NHa's never-written padding rows (>= 7200),
    // zeroed by mega_kernel block TKB (stream-ordered before tail_pipeline).
    unsigned short* NHa    = (unsigned short*)d_ws;
    unsigned short* NHb    = NHa + (size_t)PADM * 512;
    unsigned short* Tb     = NHb + (size_t)PADM * 512;
    unsigned short* mlpw_b = Tb + (size_t)PADM * CDIM;
    unsigned short* rnnw_b = mlpw_b + 65536;
    int*            idx    = (int*)(rnnw_b + 131072);
    uint*           bar    = (uint*)(NHa + (size_t)M_REAL * 512);

    mega_kernel<<<TKB + IHB + SUB, 512, 0, stream>>>(
        pts, idx, cnn, NHa, out, mlp_w, rnn_w, mlpw_b, rnnw_b, bar);

    tail_pipeline<<<GRID_B, 512, 0, stream>>>(
        NHa, NHb, Tb, idx, out, mlpw_b, rnnw_b, mlp_b, rnn_b, bar);
}

// Round 4
// 570.581 us; speedup vs baseline: 2.0641x; 1.4967x over previous
//
#include <hip/hip_runtime.h>
#include <stdint.h>

typedef unsigned int uint;
typedef unsigned long long ull;

#define HW 3600
#define CDIM 256
#define KNN 64
#define M_REAL 7200
#define PADM 7232          // 7200 padded to multiple of 64 (113*64)
#define QPB 8              // topk queries per block (one per wave)

#define TKB 900            // topk blocks
#define IHB 904            // init_h blocks (2 c-tiles each)
#define SUB 64             // setup blocks

#define GRID_B 512         // persistent tail grid: 2 blocks/CU guaranteed
#define NGATHER 900        // 8 queries each
#define NGEMMT 452         // 64x64 tiles: 113 x 4
#define LDKP 264

using short8  = __attribute__((ext_vector_type(8))) short;
using floatx4 = __attribute__((ext_vector_type(4))) float;

__device__ inline unsigned short f2bf(float f) {   // RNE fp32 -> bf16 bits
    uint u = __float_as_uint(f);
    uint r = u + 0x7FFFu + ((u >> 16) & 1u);
    return (unsigned short)(r >> 16);
}
__device__ inline float bf2f(unsigned short b) {
    return __uint_as_float(((uint)b) << 16);
}

#define WAVE_LDS_FENCE() asm volatile("s_waitcnt lgkmcnt(0)" ::: "memory")

// ---------------------------------------------------------------------------
// wave_select: threshold byte-bin from a 256-bin wave-private histogram.
// ---------------------------------------------------------------------------
__device__ inline void wave_select(uint* hist, uint* s_bin, uint* s_want,
                                   int lane, uint want) {
    uint h0 = hist[4 * lane + 0], h1 = hist[4 * lane + 1];
    uint h2 = hist[4 * lane + 2], h3 = hist[4 * lane + 3];
    hist[4 * lane + 0] = 0; hist[4 * lane + 1] = 0;
    hist[4 * lane + 2] = 0; hist[4 * lane + 3] = 0;
    uint c4 = h0 + h1 + h2 + h3;
    uint v = c4;
    #pragma unroll
    for (int off = 1; off < 64; off <<= 1) {
        uint o = __shfl_up(v, off, 64);
        if (lane >= off) v += o;
    }
    uint below = v - c4;
    if (below < want && want <= v) {
        uint b = 4 * lane, c = below;
        if (c + h0 < want) { c += h0; b = 4 * lane + 1;
            if (c + h1 < want) { c += h1; b = 4 * lane + 2;
                if (c + h2 < want) { c += h2; b = 4 * lane + 3; } } }
        *s_bin = b;
        *s_want = want - c;
    }
}

// ---------------------------------------------------------------------------
// Mega-kernel (round-0 structure, verbatim roles; 62 µs measured, VGPR 128).
// Plain launch_bounds(512): NO min-waves cap — topk needs ~128 arch VGPRs
// (round 2 proved capping to 128 unified splits 64/64 and spills 700 MB).
// Also zeroes the tail kernel's 8 barrier words (block TKB, replaces memset).
// ---------------------------------------------------------------------------
union MegaSmem {
    struct {
        float4 pts[HW];                  // 57600 B
        uint hist[QPB][256];             // 8192 B
        uint s_bin[QPB], s_want[QPB], s_cnt[QPB];
    } tk;
    struct { float tile[2][32][33]; } ih;
};

__global__ __launch_bounds__(512) void mega_kernel(
    const float* __restrict__ points, int* __restrict__ idx_out,
    const float* __restrict__ cnn, unsigned short* __restrict__ NH,
    float* __restrict__ out,
    const float* __restrict__ mw, const float* __restrict__ rw,
    unsigned short* __restrict__ mo, unsigned short* __restrict__ ro,
    uint* __restrict__ bar) {
    __shared__ MegaSmem sm;
    const int blk = blockIdx.x;

    if (blk >= TKB + IHB) {
        // ---- setup role ----
        int i0 = (blk - TKB - IHB) * 2048 + threadIdx.x * 4;
        float4 v = *(const float4*)&rw[i0];
        uint2 p;
        p.x = (uint)f2bf(v.x) | ((uint)f2bf(v.y) << 16);
        p.y = (uint)f2bf(v.z) | ((uint)f2bf(v.w) << 16);
        *(uint2*)&ro[i0] = p;
        if (i0 < 65536) {
            float4 m = *(const float4*)&mw[i0];
            p.x = (uint)f2bf(m.x) | ((uint)f2bf(m.y) << 16);
            p.y = (uint)f2bf(m.z) | ((uint)f2bf(m.w) << 16);
            *(uint2*)&mo[i0] = p;
        }
        return;
    }

    if (blk >= TKB) {
        // ---- init_h role: two 32x32 c-tiles per block ----
        if (blk == TKB && threadIdx.x < 8) bar[threadIdx.x] = 0;  // tail barriers
        const int b = blk - TKB;             // 0..903
        const int n = b / 452;
        const int r = b - n * 452;
        const int hw0 = (r % 113) * 32;
        const int c0 = (r / 113) * 64 + ((threadIdx.x >> 8) << 5);
        const int t8 = threadIdx.x & 255;
        const int tx = t8 & 31;
        const int ty = t8 >> 5;              // 0..7
        float (*tile)[33] = sm.ih.tile[threadIdx.x >> 8];
        const float* __restrict__ src = cnn + (size_t)n * CDIM * HW;
        #pragma unroll
        for (int rr = 0; rr < 4; ++rr) {
            int cc = ty + rr * 8;
            int hw = hw0 + tx;
            if (hw < HW) {
                float v = src[(size_t)(c0 + cc) * HW + hw];
                tile[cc][tx] = v;
                out[(size_t)n * (2 * CDIM * HW) + (size_t)(c0 + cc) * HW + hw] = v;
            }
        }
        __syncthreads();
        #pragma unroll
        for (int rr = 0; rr < 4; ++rr) {
            int hh = ty + rr * 8;
            int hw = hw0 + hh;
            if (hw < HW)
                NH[(size_t)(n * HW + hw) * 512 + c0 + tx] = f2bf(tile[tx][hh]);
        }
        return;
    }

    // ---- topk role ----
    const int wv = threadIdx.x >> 6;
    const int lane = threadIdx.x & 63;
    const int q = blk * QPB + wv;
    const int n = (blk * QPB) / HW;          // batch uniform per block (450 | 8)
    const int i = q - n * HW;

    const float* __restrict__ px = points + (size_t)n * 3 * HW;
    const float* __restrict__ py = px + HW;
    const float* __restrict__ pz = py + HW;

    for (int j = threadIdx.x; j < HW; j += 512)
        sm.tk.pts[j] = make_float4(px[j], py[j], pz[j], 0.0f);
    sm.tk.hist[wv][4 * lane + 0] = 0; sm.tk.hist[wv][4 * lane + 1] = 0;
    sm.tk.hist[wv][4 * lane + 2] = 0; sm.tk.hist[wv][4 * lane + 3] = 0;
    if (lane == 0) sm.tk.s_cnt[wv] = 0;
    __syncthreads();          // the ONLY block barrier: pts is block-shared

    float4 pq = sm.tk.pts[i];
    const float xi = pq.x, yi = pq.y, zi = pq.z;
    const float sqi = xi * xi + yi * yi + zi * zi;

    uint qp[29];
    #pragma unroll
    for (int s = 0; s < 57; ++s) {
        int j = (s << 6) + lane;
        uint q16 = 0xFFFFu;                  // OOB sentinel (strip 56 only)
        if (j < HW) {
            float4 p = sm.tk.pts[j];
            float d2 = fmaxf(sqi + (p.x * p.x + p.y * p.y + p.z * p.z)
                             - 2.0f * (xi * p.x + yi * p.y + zi * p.z), 0.0f);
            q16 = (uint)fminf(d2 * 1024.0f, 65535.0f);
        }
        if (s & 1) qp[s >> 1] |= q16 << 16; else qp[s >> 1] = q16;
    }
    #define Q16(s) ((qp[(s) >> 1] >> (((s) & 1) << 4)) & 0xFFFFu)

    #pragma unroll
    for (int s = 0; s < 57; ++s) {
        int j = (s << 6) + lane;
        if (j < HW) atomicAdd(&sm.tk.hist[wv][Q16(s) >> 8], 1u);
    }
    WAVE_LDS_FENCE();
    wave_select(&sm.tk.hist[wv][0], &sm.tk.s_bin[wv], &sm.tk.s_want[wv], lane, KNN);
    WAVE_LDS_FENCE();
    const uint qT8 = sm.tk.s_bin[wv];
    const uint want2 = sm.tk.s_want[wv];

    #pragma unroll
    for (int s = 0; s < 57; ++s) {
        int j = (s << 6) + lane;
        uint k = Q16(s);
        if (j < HW && (k >> 8) == qT8)
            atomicAdd(&sm.tk.hist[wv][k & 255u], 1u);
    }
    WAVE_LDS_FENCE();
    wave_select(&sm.tk.hist[wv][0], &sm.tk.s_bin[wv], &sm.tk.s_want[wv], lane, want2);
    WAVE_LDS_FENCE();
    const uint qT16 = (qT8 << 8) | sm.tk.s_bin[wv];
    const uint want3 = sm.tk.s_want[wv];

    #pragma unroll
    for (int s = 0; s < 57; ++s) {
        if (Q16(s) < qT16) {
            uint pos = atomicAdd(&sm.tk.s_cnt[wv], 1u);
            if (pos < KNN) idx_out[(size_t)q * KNN + pos] = (s << 6) + lane;
        }
    }

    ull cand[4] = {~0ULL, ~0ULL, ~0ULL, ~0ULL};
    int ncand = 0;
    #pragma unroll
    for (int s = 0; s < 57; ++s) {
        int j = (s << 6) + lane;
        if (j < HW && Q16(s) == qT16) {
            float4 p = sm.tk.pts[j];
            float d2 = fmaxf(sqi + (p.x * p.x + p.y * p.y + p.z * p.z)
                             - 2.0f * (xi * p.x + yi * p.y + zi * p.z), 0.0f);
            ull key = ((ull)__float_as_uint(d2) << 32) | (uint)j;
            if      (ncand == 0) cand[0] = key;
            else if (ncand == 1) cand[1] = key;
            else if (ncand == 2) cand[2] = key;
            else if (ncand == 3) cand[3] = key;
            ++ncand;
        }
    }
    const int base = KNN - (int)want3;
    if (__ballot(ncand > 4) == 0ULL) {
        for (int r = 0; r < (int)want3; ++r) {
            ull best = cand[0] < cand[1] ? cand[0] : cand[1];
            ull b23  = cand[2] < cand[3] ? cand[2] : cand[3];
            best = best < b23 ? best : b23;
            #pragma unroll
            for (int off = 1; off < 64; off <<= 1) {
                ull o = __shfl_xor(best, off, 64);
                if (o < best) best = o;
            }
            if (lane == 0) idx_out[(size_t)q * KNN + base + r] = (int)(uint)best;
            #pragma unroll
            for (int c = 0; c < 4; ++c)
                if (cand[c] == best) cand[c] = ~0ULL;
        }
    } else {
        ull used = 0ULL;
        for (int r = 0; r < (int)want3; ++r) {
            ull best = ~0ULL;
            #pragma unroll
            for (int s = 0; s < 57; ++s) {
                int j = (s << 6) + lane;
                if (j < HW && Q16(s) == qT16 && !((used >> s) & 1ULL)) {
                    float4 p = sm.tk.pts[j];
                    float d2 = fmaxf(sqi + (p.x * p.x + p.y * p.y + p.z * p.z)
                                     - 2.0f * (xi * p.x + yi * p.y + zi * p.z), 0.0f);
                    ull key = ((ull)__float_as_uint(d2) << 32) | (uint)j;
                    if (key < best) best = key;
                }
            }
            #pragma unroll
            for (int off = 1; off < 64; off <<= 1) {
                ull o = __shfl_xor(best, off, 64);
                if (o < best) best = o;
            }
            uint jw = (uint)best;
            if (lane == 0) idx_out[(size_t)q * KNN + base + r] = (int)jw;
            if ((int)(jw & 63u) == lane) used |= 1ULL << (jw >> 6);
        }
    }
    #undef Q16
}

// ---------------------------------------------------------------------------
// Persistent tail: gather/gemm bodies only (low register pressure, so the
// (512,4) co-residency cap cannot spill). 2 blocks/CU guaranteed:
// LDS 67584 <= 80K, VGPR capped 128 -> 16 waves/CU.
// ---------------------------------------------------------------------------
struct GeSmem { unsigned short As[64 * LDKP]; unsigned short Bs[64 * LDKP]; };

// Grid barrier, cooperative-groups style. Round-3 version spun on an
// ACQUIRE agent load -> per-poll L1/L2 invalidation storm (~90 µs/barrier,
// phases crawled at 50 GB/s). Fix: release ONCE via the RMW, spin RELAXED
// (atomics bypass cache; no invalidation), acquire-fence ONCE after the wait.
__device__ inline void gsync(uint* bar, int i) {
    __syncthreads();
    if (threadIdx.x == 0) {
        uint t = __hip_atomic_fetch_add(&bar[i], 1u, __ATOMIC_RELEASE,
                                        __HIP_MEMORY_SCOPE_AGENT);
        uint target = (t / GRID_B + 1u) * GRID_B;
        while (__hip_atomic_load(&bar[i], __ATOMIC_RELAXED,
                                 __HIP_MEMORY_SCOPE_AGENT) < target)
            __builtin_amdgcn_s_sleep(8);
        __builtin_amdgcn_fence(__ATOMIC_ACQUIRE, "agent");  // one-shot inv
    }
    __syncthreads();
}

// gather body: 8 queries per virtual block (one/wave), no LDS.
static __device__ void gather_body(int g, const unsigned short* __restrict__ T,
                                   const int* __restrict__ idx,
                                   unsigned short* __restrict__ NH) {
    const int q = g * 8 + (threadIdx.x >> 6);
    const int lane = threadIdx.x & 63;
    const int n = q / HW;
    const int half = lane >> 5;
    const int c8 = (lane & 31) * 8;

    const int nbrL = idx[(size_t)q * KNN + lane];
    float acc[8] = {0, 0, 0, 0, 0, 0, 0, 0};
    #pragma unroll 4
    for (int it = 0; it < 32; ++it) {
        int k = 2 * it + half;
        int j = __shfl(nbrL, k, 64);
        j = min(max(j, 0), HW - 1);
        int r = n * HW + j;
        uint4 v = *(const uint4*)&T[(size_t)r * CDIM + c8];
        acc[0] += bf2f((unsigned short)(v.x & 0xFFFFu));
        acc[1] += bf2f((unsigned short)(v.x >> 16));
        acc[2] += bf2f((unsigned short)(v.y & 0xFFFFu));
        acc[3] += bf2f((unsigned short)(v.y >> 16));
        acc[4] += bf2f((unsigned short)(v.z & 0xFFFFu));
        acc[5] += bf2f((unsigned short)(v.z >> 16));
        acc[6] += bf2f((unsigned short)(v.w & 0xFFFFu));
        acc[7] += bf2f((unsigned short)(v.w >> 16));
    }
    #pragma unroll
    for (int c = 0; c < 8; ++c) acc[c] += __shfl_xor(acc[c], 32, 64);
    if (half == 0) {
        uint4 o;
        o.x = (uint)f2bf(acc[0] * (1.0f / KNN)) | ((uint)f2bf(acc[1] * (1.0f / KNN)) << 16);
        o.y = (uint)f2bf(acc[2] * (1.0f / KNN)) | ((uint)f2bf(acc[3] * (1.0f / KNN)) << 16);
        o.z = (uint)f2bf(acc[4] * (1.0f / KNN)) | ((uint)f2bf(acc[5] * (1.0f / KNN)) << 16);
        o.w = (uint)f2bf(acc[6] * (1.0f / KNN)) | ((uint)f2bf(acc[7] * (1.0f / KNN)) << 16);
        *(uint4*)&NH[(size_t)q * 512 + CDIM + c8] = o;
    }
}

// bf16 MFMA GEMM body, 512 threads / 8 waves, 64x64 tile, BK=256 chunks.
// Threads 0-255 stage As, 256-511 stage Bs. Wave tile 32x16 (2x1 frags).
// All stores guarded mb<M_REAL: keeps NHa/NHb padding rows (incl. barrier
// words) clean. Garbage padding rows of A only affect discarded C rows.
static __device__ void gemm_body(GeSmem& sm, int v,
    const unsigned short* __restrict__ A, int lda,
    const unsigned short* __restrict__ W, int ldw,
    const float* __restrict__ bias,
    unsigned short* __restrict__ Cb, int ldc,
    float* __restrict__ outp, int mode, int Kk) {
    const int m0 = (v % 113) * 64;
    const int n0 = (v / 113) * 64;
    const int tid = threadIdx.x;
    const int lane = tid & 63;
    const int w = tid >> 6;
    const int wm = (w & 1) * 32;
    const int wn = (w >> 1) * 16;
    const int l15 = lane & 15;
    const int qd = lane >> 4;

    const int tt = tid & 255;
    const int mat = tid >> 8;                 // 0: A, 1: B
    const int srow = tt >> 5;                 // 0..7
    const int scol = (tt & 31) * 8;           // 16B chunks across 256 cols
    const unsigned short* __restrict__ S = mat ? W : A;
    const int lds_ = mat ? ldw : lda;
    unsigned short* dst = mat ? sm.Bs : sm.As;
    const int rbase = mat ? n0 : m0;

    floatx4 acc0 = (floatx4){0.f, 0.f, 0.f, 0.f};
    floatx4 acc1 = (floatx4){0.f, 0.f, 0.f, 0.f};

    for (int k0 = 0; k0 < Kk; k0 += 256) {
        __syncthreads();
        #pragma unroll
        for (int r8 = 0; r8 < 8; ++r8) {
            int row = r8 * 8 + srow;
            *(float4*)&dst[row * LDKP + scol] =
                *(const float4*)&S[(size_t)(rbase + row) * lds_ + k0 + scol];
        }
        __syncthreads();
        #pragma unroll
        for (int ks = 0; ks < 256; ks += 32) {
            short8 a0 = *(const short8*)&sm.As[(wm + l15) * LDKP + ks + qd * 8];
            short8 a1 = *(const short8*)&sm.As[(wm + 16 + l15) * LDKP + ks + qd * 8];
            short8 b0 = *(const short8*)&sm.Bs[(wn + l15) * LDKP + ks + qd * 8];
            acc0 = __builtin_amdgcn_mfma_f32_16x16x32_bf16(a0, b0, acc0, 0, 0, 0);
            acc1 = __builtin_amdgcn_mfma_f32_16x16x32_bf16(a1, b0, acc1, 0, 0, 0);
        }
    }

    const int col = n0 + wn + l15;
    const float bv = bias[col];
    #pragma unroll
    for (int im = 0; im < 2; ++im) {
        int mb = m0 + wm + im * 16 + qd * 4;
        floatx4 a = im ? acc1 : acc0;
        if (mb < M_REAL) {
            if (mode == 0) {
                #pragma unroll
                for (int r = 0; r < 4; ++r)
                    Cb[(size_t)(mb + r) * ldc + col] =
                        f2bf(fmaxf(a[r] + bv, 0.0f));
            } else {
                int nb = mb / HW;
                int hw = mb - nb * HW;
                float4 o;
                o.x = fmaxf(a[0] + bv, 0.0f);
                o.y = fmaxf(a[1] + bv, 0.0f);
                o.z = fmaxf(a[2] + bv, 0.0f);
                o.w = fmaxf(a[3] + bv, 0.0f);
                *(float4*)&outp[(size_t)nb * (2 * CDIM * HW)
                                + (size_t)(CDIM + col) * HW + hw] = o;
            }
        }
    }
}

__global__ __launch_bounds__(512, 4) void tail_pipeline(
    unsigned short* __restrict__ NHa, unsigned short* __restrict__ NHb,
    unsigned short* __restrict__ Tb, const int* __restrict__ idx,
    float* __restrict__ out,
    const unsigned short* __restrict__ mo, const unsigned short* __restrict__ ro,
    const float* __restrict__ mb_, const float* __restrict__ rb_,
    uint* __restrict__ bar) {
    __shared__ GeSmem sm;
    const int blk = blockIdx.x;

    // ---- it 0 ----
    if (blk < NGEMMT) gemm_body(sm, blk, NHa, 512, mo, CDIM, mb_, Tb, CDIM, nullptr, 0, CDIM);
    gsync(bar, 0);
    for (int g = blk; g < NGATHER; g += GRID_B) gather_body(g, Tb, idx, NHa);
    gsync(bar, 1);
    if (blk < NGEMMT) gemm_body(sm, blk, NHa, 512, ro, 512, rb_, NHb, 512, nullptr, 0, 512);
    gsync(bar, 2);

    // ---- it 1 ----
    if (blk < NGEMMT) gemm_body(sm, blk, NHb, 512, mo, CDIM, mb_, Tb, CDIM, nullptr, 0, CDIM);
    gsync(bar, 3);
    for (int g = blk; g < NGATHER; g += GRID_B) gather_body(g, Tb, idx, NHb);
    gsync(bar, 4);
    if (blk < NGEMMT) gemm_body(sm, blk, NHb, 512, ro, 512, rb_, NHa, 512, nullptr, 0, 512);
    gsync(bar, 5);

    // ---- it 2 ----
    if (blk < NGEMMT) gemm_body(sm, blk, NHa, 512, mo, CDIM, mb_, Tb, CDIM, nullptr, 0, CDIM);
    gsync(bar, 6);
    for (int g = blk; g < NGATHER; g += GRID_B) gather_body(g, Tb, idx, NHa);
    gsync(bar, 7);
    if (blk < NGEMMT) gemm_body(sm, blk, NHa, 512, ro, 512, rb_, nullptr, 0, out, 1, 512);
}

extern "C" void kernel_launch(void* const* d_in, const int* in_sizes, int n_in,
                              void* d_out, int out_size, void* d_ws, size_t ws_size,
                              hipStream_t stream) {
    const float* cnn   = (const float*)d_in[0];
    const float* pts   = (const float*)d_in[1];
    const float* mlp_w = (const float*)d_in[2];
    const float* mlp_b = (const float*)d_in[3];
    const float* rnn_w = (const float*)d_in[4];
    const float* rnn_b = (const float*)d_in[5];
    float* out = (float*)d_out;

    // workspace (unchanged footprint):
    // NHa(7232x512 u16) | NHb(7232x512 u16) | Tb(7232x256 u16)
    // | mlpw_b(65536 u16) | rnnw_b(131072 u16) | idx(7200x64 int)
    // barrier counters live in NHa's never-written padding rows (>= 7200),
    // zeroed by mega_kernel block TKB (stream-ordered before tail_pipeline).
    unsigned short* NHa    = (unsigned short*)d_ws;
    unsigned short* NHb    = NHa + (size_t)PADM * 512;
    unsigned short* Tb     = NHb + (size_t)PADM * 512;
    unsigned short* mlpw_b = Tb + (size_t)PADM * CDIM;
    unsigned short* rnnw_b = mlpw_b + 65536;
    int*            idx    = (int*)(rnnw_b + 131072);
    uint*           bar    = (uint*)(NHa + (size_t)M_REAL * 512);

    mega_kernel<<<TKB + IHB + SUB, 512, 0, stream>>>(
        pts, idx, cnn, NHa, out, mlp_w, rnn_w, mlpw_b, rnnw_b, bar);

    tail_pipeline<<<GRID_B, 512, 0, stream>>>(
        NHa, NHb, Tb, idx, out, mlpw_b, rnnw_b, mlp_b, rnn_b, bar);
}

// Round 5
// 209.895 us; speedup vs baseline: 5.6109x; 2.7184x over previous
//
#include <hip/hip_runtime.h>
#include <stdint.h>

typedef unsigned int uint;
typedef unsigned long long ull;

#define HW 3600
#define CDIM 256
#define KNN 64
#define M_REAL 7200
#define PADM 7232          // 7200 padded to multiple of 64 (113*64)
#define QPB 8              // topk queries per block (one per wave)

#define TKB 900            // topk blocks
#define IHB 904            // init_h blocks (2 c-tiles each)
#define SUB 64             // setup blocks

#define LDB2 136           // BK=128 LDS row pitch (shorts): 272B, bank-free class

using short8  = __attribute__((ext_vector_type(8))) short;
using floatx4 = __attribute__((ext_vector_type(4))) float;

__device__ inline unsigned short f2bf(float f) {   // RNE fp32 -> bf16 bits
    uint u = __float_as_uint(f);
    uint r = u + 0x7FFFu + ((u >> 16) & 1u);
    return (unsigned short)(r >> 16);
}
__device__ inline float bf2f(unsigned short b) {
    return __uint_as_float(((uint)b) << 16);
}

#define WAVE_LDS_FENCE() asm volatile("s_waitcnt lgkmcnt(0)" ::: "memory")

// ---------------------------------------------------------------------------
// wave_select: threshold byte-bin from a 256-bin wave-private histogram.
// ---------------------------------------------------------------------------
__device__ inline void wave_select(uint* hist, uint* s_bin, uint* s_want,
                                   int lane, uint want) {
    uint h0 = hist[4 * lane + 0], h1 = hist[4 * lane + 1];
    uint h2 = hist[4 * lane + 2], h3 = hist[4 * lane + 3];
    hist[4 * lane + 0] = 0; hist[4 * lane + 1] = 0;
    hist[4 * lane + 2] = 0; hist[4 * lane + 3] = 0;
    uint c4 = h0 + h1 + h2 + h3;
    uint v = c4;
    #pragma unroll
    for (int off = 1; off < 64; off <<= 1) {
        uint o = __shfl_up(v, off, 64);
        if (lane >= off) v += o;
    }
    uint below = v - c4;
    if (below < want && want <= v) {
        uint b = 4 * lane, c = below;
        if (c + h0 < want) { c += h0; b = 4 * lane + 1;
            if (c + h1 < want) { c += h1; b = 4 * lane + 2;
                if (c + h2 < want) { c += h2; b = 4 * lane + 3; } } }
        *s_bin = b;
        *s_want = want - c;
    }
}

// ---------------------------------------------------------------------------
// Mega-kernel: round-0 structure verbatim (62 µs measured, VGPR 128).
// Roles: topk [0,900), init_h [900,1804), setup [1804,1868).
// ---------------------------------------------------------------------------
union MegaSmem {
    struct {
        float4 pts[HW];                  // 57600 B
        uint hist[QPB][256];             // 8192 B
        uint s_bin[QPB], s_want[QPB], s_cnt[QPB];
    } tk;
    struct { float tile[2][32][33]; } ih;
};

__global__ __launch_bounds__(512) void mega_kernel(
    const float* __restrict__ points, int* __restrict__ idx_out,
    const float* __restrict__ cnn, unsigned short* __restrict__ NH,
    float* __restrict__ out,
    const float* __restrict__ mw, const float* __restrict__ rw,
    unsigned short* __restrict__ mo, unsigned short* __restrict__ ro) {
    __shared__ MegaSmem sm;
    const int blk = blockIdx.x;

    if (blk >= TKB + IHB) {
        // ---- setup role: weights fp32 -> bf16 ----
        int i0 = (blk - TKB - IHB) * 2048 + threadIdx.x * 4;
        float4 v = *(const float4*)&rw[i0];
        uint2 p;
        p.x = (uint)f2bf(v.x) | ((uint)f2bf(v.y) << 16);
        p.y = (uint)f2bf(v.z) | ((uint)f2bf(v.w) << 16);
        *(uint2*)&ro[i0] = p;
        if (i0 < 65536) {
            float4 m = *(const float4*)&mw[i0];
            p.x = (uint)f2bf(m.x) | ((uint)f2bf(m.y) << 16);
            p.y = (uint)f2bf(m.z) | ((uint)f2bf(m.w) << 16);
            *(uint2*)&mo[i0] = p;
        }
        return;
    }

    if (blk >= TKB) {
        // ---- init_h role: two 32x32 c-tiles per block ----
        const int b = blk - TKB;             // 0..903
        const int n = b / 452;
        const int r = b - n * 452;
        const int hw0 = (r % 113) * 32;
        const int c0 = (r / 113) * 64 + ((threadIdx.x >> 8) << 5);
        const int t8 = threadIdx.x & 255;
        const int tx = t8 & 31;
        const int ty = t8 >> 5;              // 0..7
        float (*tile)[33] = sm.ih.tile[threadIdx.x >> 8];
        const float* __restrict__ src = cnn + (size_t)n * CDIM * HW;
        #pragma unroll
        for (int rr = 0; rr < 4; ++rr) {
            int cc = ty + rr * 8;
            int hw = hw0 + tx;
            if (hw < HW) {
                float v = src[(size_t)(c0 + cc) * HW + hw];
                tile[cc][tx] = v;
                out[(size_t)n * (2 * CDIM * HW) + (size_t)(c0 + cc) * HW + hw] = v;
            }
        }
        __syncthreads();
        #pragma unroll
        for (int rr = 0; rr < 4; ++rr) {
            int hh = ty + rr * 8;
            int hw = hw0 + hh;
            if (hw < HW)
                NH[(size_t)(n * HW + hw) * 512 + c0 + tx] = f2bf(tile[tx][hh]);
        }
        return;
    }

    // ---- topk role ----
    const int wv = threadIdx.x >> 6;
    const int lane = threadIdx.x & 63;
    const int q = blk * QPB + wv;
    const int n = (blk * QPB) / HW;          // batch uniform per block (450 | 8)
    const int i = q - n * HW;

    const float* __restrict__ px = points + (size_t)n * 3 * HW;
    const float* __restrict__ py = px + HW;
    const float* __restrict__ pz = py + HW;

    for (int j = threadIdx.x; j < HW; j += 512)
        sm.tk.pts[j] = make_float4(px[j], py[j], pz[j], 0.0f);
    sm.tk.hist[wv][4 * lane + 0] = 0; sm.tk.hist[wv][4 * lane + 1] = 0;
    sm.tk.hist[wv][4 * lane + 2] = 0; sm.tk.hist[wv][4 * lane + 3] = 0;
    if (lane == 0) sm.tk.s_cnt[wv] = 0;
    __syncthreads();          // the ONLY block barrier: pts is block-shared

    float4 pq = sm.tk.pts[i];
    const float xi = pq.x, yi = pq.y, zi = pq.z;
    const float sqi = xi * xi + yi * yi + zi * zi;

    uint qp[29];
    #pragma unroll
    for (int s = 0; s < 57; ++s) {
        int j = (s << 6) + lane;
        uint q16 = 0xFFFFu;                  // OOB sentinel (strip 56 only)
        if (j < HW) {
            float4 p = sm.tk.pts[j];
            float d2 = fmaxf(sqi + (p.x * p.x + p.y * p.y + p.z * p.z)
                             - 2.0f * (xi * p.x + yi * p.y + zi * p.z), 0.0f);
            q16 = (uint)fminf(d2 * 1024.0f, 65535.0f);
        }
        if (s & 1) qp[s >> 1] |= q16 << 16; else qp[s >> 1] = q16;
    }
    #define Q16(s) ((qp[(s) >> 1] >> (((s) & 1) << 4)) & 0xFFFFu)

    #pragma unroll
    for (int s = 0; s < 57; ++s) {
        int j = (s << 6) + lane;
        if (j < HW) atomicAdd(&sm.tk.hist[wv][Q16(s) >> 8], 1u);
    }
    WAVE_LDS_FENCE();
    wave_select(&sm.tk.hist[wv][0], &sm.tk.s_bin[wv], &sm.tk.s_want[wv], lane, KNN);
    WAVE_LDS_FENCE();
    const uint qT8 = sm.tk.s_bin[wv];
    const uint want2 = sm.tk.s_want[wv];

    #pragma unroll
    for (int s = 0; s < 57; ++s) {
        int j = (s << 6) + lane;
        uint k = Q16(s);
        if (j < HW && (k >> 8) == qT8)
            atomicAdd(&sm.tk.hist[wv][k & 255u], 1u);
    }
    WAVE_LDS_FENCE();
    wave_select(&sm.tk.hist[wv][0], &sm.tk.s_bin[wv], &sm.tk.s_want[wv], lane, want2);
    WAVE_LDS_FENCE();
    const uint qT16 = (qT8 << 8) | sm.tk.s_bin[wv];
    const uint want3 = sm.tk.s_want[wv];

    #pragma unroll
    for (int s = 0; s < 57; ++s) {
        if (Q16(s) < qT16) {
            uint pos = atomicAdd(&sm.tk.s_cnt[wv], 1u);
            if (pos < KNN) idx_out[(size_t)q * KNN + pos] = (s << 6) + lane;
        }
    }

    ull cand[4] = {~0ULL, ~0ULL, ~0ULL, ~0ULL};
    int ncand = 0;
    #pragma unroll
    for (int s = 0; s < 57; ++s) {
        int j = (s << 6) + lane;
        if (j < HW && Q16(s) == qT16) {
            float4 p = sm.tk.pts[j];
            float d2 = fmaxf(sqi + (p.x * p.x + p.y * p.y + p.z * p.z)
                             - 2.0f * (xi * p.x + yi * p.y + zi * p.z), 0.0f);
            ull key = ((ull)__float_as_uint(d2) << 32) | (uint)j;
            if      (ncand == 0) cand[0] = key;
            else if (ncand == 1) cand[1] = key;
            else if (ncand == 2) cand[2] = key;
            else if (ncand == 3) cand[3] = key;
            ++ncand;
        }
    }
    const int base = KNN - (int)want3;
    if (__ballot(ncand > 4) == 0ULL) {
        for (int r = 0; r < (int)want3; ++r) {
            ull best = cand[0] < cand[1] ? cand[0] : cand[1];
            ull b23  = cand[2] < cand[3] ? cand[2] : cand[3];
            best = best < b23 ? best : b23;
            #pragma unroll
            for (int off = 1; off < 64; off <<= 1) {
                ull o = __shfl_xor(best, off, 64);
                if (o < best) best = o;
            }
            if (lane == 0) idx_out[(size_t)q * KNN + base + r] = (int)(uint)best;
            #pragma unroll
            for (int c = 0; c < 4; ++c)
                if (cand[c] == best) cand[c] = ~0ULL;
        }
    } else {
        ull used = 0ULL;
        for (int r = 0; r < (int)want3; ++r) {
            ull best = ~0ULL;
            #pragma unroll
            for (int s = 0; s < 57; ++s) {
                int j = (s << 6) + lane;
                if (j < HW && Q16(s) == qT16 && !((used >> s) & 1ULL)) {
                    float4 p = sm.tk.pts[j];
                    float d2 = fmaxf(sqi + (p.x * p.x + p.y * p.y + p.z * p.z)
                                     - 2.0f * (xi * p.x + yi * p.y + zi * p.z), 0.0f);
                    ull key = ((ull)__float_as_uint(d2) << 32) | (uint)j;
                    if (key < best) best = key;
                }
            }
            #pragma unroll
            for (int off = 1; off < 64; off <<= 1) {
                ull o = __shfl_xor(best, off, 64);
                if (o < best) best = o;
            }
            uint jw = (uint)best;
            if (lane == 0) idx_out[(size_t)q * KNN + base + r] = (int)jw;
            if ((int)(jw & 63u) == lane) used |= 1ULL << (jw >> 6);
        }
    }
    #undef Q16
}

// ---------------------------------------------------------------------------
// Shared GEMM core geometry (BK=128, LDS 34.8 KB -> 4 blocks/CU, 16 waves/CU):
// 256 threads / 4 waves, 64x64 tile, wave = 32x32 (2x2 frags of 16x16x32).
// Staging: srow=tid>>4 (0..15), scol=(tid&15)*8; 4 row-groups of 16.
// ---------------------------------------------------------------------------

// D1: dual GEMM, 904 blocks. v<452: Tb = relu(mlp_w . h + mb)  [bf16]
//                            v>=452: P = Wh . h + rb           [fp32, no relu]
// Wh = rnn_w k-cols 0..255. Both read A = NH left half (lda 512).
__global__ __launch_bounds__(256) void gemm_dual(
    const unsigned short* __restrict__ NH,
    const unsigned short* __restrict__ mwb,  // mlp weights bf16, ldw 256
    const float* __restrict__ mbias,
    const unsigned short* __restrict__ rwb,  // rnn weights bf16, ldw 512
    const float* __restrict__ rbias,
    unsigned short* __restrict__ Tb,         // ldc 256
    float* __restrict__ P) {                 // ldc 256
    __shared__ __align__(16) unsigned short As[64 * LDB2];
    __shared__ __align__(16) unsigned short Bs[64 * LDB2];
    const int v = blockIdx.x;
    const bool is_mlp = v < 452;
    const int g = is_mlp ? v : v - 452;
    const int m0 = (g % 113) * 64;
    const int n0 = (g / 113) * 64;
    const unsigned short* __restrict__ W = is_mlp ? mwb : rwb;
    const int ldw = is_mlp ? 256 : 512;

    const int tid = threadIdx.x;
    const int lane = tid & 63;
    const int w = tid >> 6;
    const int wm = (w & 1) * 32;
    const int wn = (w >> 1) * 32;
    const int l15 = lane & 15;
    const int qd = lane >> 4;                // quad 0..3

    floatx4 acc[2][2];
    #pragma unroll
    for (int a = 0; a < 2; ++a)
        #pragma unroll
        for (int b = 0; b < 2; ++b)
            acc[a][b] = (floatx4){0.f, 0.f, 0.f, 0.f};

    const int srow = tid >> 4;               // 0..15
    const int scol = (tid & 15) * 8;         // 16B chunks across 128 cols

    for (int kc = 0; kc < 256; kc += 128) {
        if (kc) __syncthreads();
        #pragma unroll
        for (int r4 = 0; r4 < 4; ++r4) {
            int row = r4 * 16 + srow;
            *(float4*)&As[row * LDB2 + scol] =
                *(const float4*)&NH[(size_t)(m0 + row) * 512 + kc + scol];
            *(float4*)&Bs[row * LDB2 + scol] =
                *(const float4*)&W[(size_t)(n0 + row) * ldw + kc + scol];
        }
        __syncthreads();
        #pragma unroll
        for (int ks = 0; ks < 128; ks += 32) {
            short8 a0 = *(const short8*)&As[(wm + l15) * LDB2 + ks + qd * 8];
            short8 a1 = *(const short8*)&As[(wm + 16 + l15) * LDB2 + ks + qd * 8];
            short8 b0 = *(const short8*)&Bs[(wn + l15) * LDB2 + ks + qd * 8];
            short8 b1 = *(const short8*)&Bs[(wn + 16 + l15) * LDB2 + ks + qd * 8];
            acc[0][0] = __builtin_amdgcn_mfma_f32_16x16x32_bf16(a0, b0, acc[0][0], 0, 0, 0);
            acc[0][1] = __builtin_amdgcn_mfma_f32_16x16x32_bf16(a0, b1, acc[0][1], 0, 0, 0);
            acc[1][0] = __builtin_amdgcn_mfma_f32_16x16x32_bf16(a1, b0, acc[1][0], 0, 0, 0);
            acc[1][1] = __builtin_amdgcn_mfma_f32_16x16x32_bf16(a1, b1, acc[1][1], 0, 0, 0);
        }
    }

    #pragma unroll
    for (int in = 0; in < 2; ++in) {
        int col = n0 + wn + in * 16 + l15;
        float bv = is_mlp ? mbias[col] : rbias[col];
        #pragma unroll
        for (int im = 0; im < 2; ++im) {
            int mb = m0 + wm + im * 16 + qd * 4;
            if (is_mlp) {
                #pragma unroll
                for (int r = 0; r < 4; ++r)
                    Tb[(size_t)(mb + r) * CDIM + col] =
                        f2bf(fmaxf(acc[im][in][r] + bv, 0.0f));
            } else {
                #pragma unroll
                for (int r = 0; r < 4; ++r)
                    P[(size_t)(mb + r) * CDIM + col] = acc[im][in][r] + bv;
            }
        }
    }
}

// D3: rnn second half, 452 blocks. acc = Wm . msg (K=256);
// h' = relu(acc + P). mode 0: bf16 store to NH LEFT half (in-place; reads
// only the right half, so disjoint). mode 1: fp32 transpose-store into out.
__global__ __launch_bounds__(256) void gemm_rnn2(
    const unsigned short* __restrict__ NH,   // A = NH right half (lda 512)
    const unsigned short* __restrict__ rwb,  // Wm = rnn_w k-cols 256..511
    const float* __restrict__ P,
    unsigned short* __restrict__ Cb,         // NH base (ldc 512), mode 0
    float* __restrict__ outp, int mode) {
    __shared__ __align__(16) unsigned short As[64 * LDB2];
    __shared__ __align__(16) unsigned short Bs[64 * LDB2];
    const int m0 = (blockIdx.x % 113) * 64;
    const int n0 = (blockIdx.x / 113) * 64;

    const int tid = threadIdx.x;
    const int lane = tid & 63;
    const int w = tid >> 6;
    const int wm = (w & 1) * 32;
    const int wn = (w >> 1) * 32;
    const int l15 = lane & 15;
    const int qd = lane >> 4;

    floatx4 acc[2][2];
    #pragma unroll
    for (int a = 0; a < 2; ++a)
        #pragma unroll
        for (int b = 0; b < 2; ++b)
            acc[a][b] = (floatx4){0.f, 0.f, 0.f, 0.f};

    const int srow = tid >> 4;
    const int scol = (tid & 15) * 8;

    for (int kc = 0; kc < 256; kc += 128) {
        if (kc) __syncthreads();
        #pragma unroll
        for (int r4 = 0; r4 < 4; ++r4) {
            int row = r4 * 16 + srow;
            *(float4*)&As[row * LDB2 + scol] =
                *(const float4*)&NH[(size_t)(m0 + row) * 512 + 256 + kc + scol];
            *(float4*)&Bs[row * LDB2 + scol] =
                *(const float4*)&rwb[(size_t)(n0 + row) * 512 + 256 + kc + scol];
        }
        __syncthreads();
        #pragma unroll
        for (int ks = 0; ks < 128; ks += 32) {
            short8 a0 = *(const short8*)&As[(wm + l15) * LDB2 + ks + qd * 8];
            short8 a1 = *(const short8*)&As[(wm + 16 + l15) * LDB2 + ks + qd * 8];
            short8 b0 = *(const short8*)&Bs[(wn + l15) * LDB2 + ks + qd * 8];
            short8 b1 = *(const short8*)&Bs[(wn + 16 + l15) * LDB2 + ks + qd * 8];
            acc[0][0] = __builtin_amdgcn_mfma_f32_16x16x32_bf16(a0, b0, acc[0][0], 0, 0, 0);
            acc[0][1] = __builtin_amdgcn_mfma_f32_16x16x32_bf16(a0, b1, acc[0][1], 0, 0, 0);
            acc[1][0] = __builtin_amdgcn_mfma_f32_16x16x32_bf16(a1, b0, acc[1][0], 0, 0, 0);
            acc[1][1] = __builtin_amdgcn_mfma_f32_16x16x32_bf16(a1, b1, acc[1][1], 0, 0, 0);
        }
    }

    #pragma unroll
    for (int in = 0; in < 2; ++in) {
        int col = n0 + wn + in * 16 + l15;
        #pragma unroll
        for (int im = 0; im < 2; ++im) {
            int mb = m0 + wm + im * 16 + qd * 4;
            if (mode == 0) {
                #pragma unroll
                for (int r = 0; r < 4; ++r) {
                    float o = fmaxf(acc[im][in][r] + P[(size_t)(mb + r) * CDIM + col], 0.0f);
                    Cb[(size_t)(mb + r) * 512 + col] = f2bf(o);
                }
            } else if (mb < M_REAL) {
                int nb = mb / HW;
                int hw = mb - nb * HW;
                float4 o;
                o.x = fmaxf(acc[im][in][0] + P[(size_t)(mb + 0) * CDIM + col], 0.0f);
                o.y = fmaxf(acc[im][in][1] + P[(size_t)(mb + 1) * CDIM + col], 0.0f);
                o.z = fmaxf(acc[im][in][2] + P[(size_t)(mb + 2) * CDIM + col], 0.0f);
                o.w = fmaxf(acc[im][in][3] + P[(size_t)(mb + 3) * CDIM + col], 0.0f);
                *(float4*)&outp[(size_t)nb * (2 * CDIM * HW)
                                + (size_t)(CDIM + col) * HW + hw] = o;
            }
        }
    }
}

// ---------------------------------------------------------------------------
// message[q][c] = (1/64)*sum_k T[n*HW+idx[q][k]][c] -> NH right half (bf16)
// ---------------------------------------------------------------------------
__global__ __launch_bounds__(256) void gather_mean(const unsigned short* __restrict__ T,
                                                   const int* __restrict__ idx,
                                                   unsigned short* __restrict__ NH) {
    const int q = blockIdx.x * 4 + (threadIdx.x >> 6);
    const int lane = threadIdx.x & 63;
    const int n = q / HW;
    const int half = lane >> 5;           // k parity
    const int c8 = (lane & 31) * 8;       // 8-col strip

    const int nbrL = idx[(size_t)q * KNN + lane];
    float acc[8] = {0, 0, 0, 0, 0, 0, 0, 0};
    #pragma unroll 4
    for (int it = 0; it < 32; ++it) {
        int k = 2 * it + half;
        int j = __shfl(nbrL, k, 64);
        j = min(max(j, 0), HW - 1);       // defensive clamp
        int r = n * HW + j;
        uint4 v = *(const uint4*)&T[(size_t)r * CDIM + c8];
        acc[0] += bf2f((unsigned short)(v.x & 0xFFFFu));
        acc[1] += bf2f((unsigned short)(v.x >> 16));
        acc[2] += bf2f((unsigned short)(v.y & 0xFFFFu));
        acc[3] += bf2f((unsigned short)(v.y >> 16));
        acc[4] += bf2f((unsigned short)(v.z & 0xFFFFu));
        acc[5] += bf2f((unsigned short)(v.z >> 16));
        acc[6] += bf2f((unsigned short)(v.w & 0xFFFFu));
        acc[7] += bf2f((unsigned short)(v.w >> 16));
    }
    #pragma unroll
    for (int c = 0; c < 8; ++c) acc[c] += __shfl_xor(acc[c], 32, 64);
    if (half == 0) {
        uint4 o;
        o.x = (uint)f2bf(acc[0] * (1.0f / KNN)) | ((uint)f2bf(acc[1] * (1.0f / KNN)) << 16);
        o.y = (uint)f2bf(acc[2] * (1.0f / KNN)) | ((uint)f2bf(acc[3] * (1.0f / KNN)) << 16);
        o.z = (uint)f2bf(acc[4] * (1.0f / KNN)) | ((uint)f2bf(acc[5] * (1.0f / KNN)) << 16);
        o.w = (uint)f2bf(acc[6] * (1.0f / KNN)) | ((uint)f2bf(acc[7] * (1.0f / KNN)) << 16);
        *(uint4*)&NH[(size_t)q * 512 + CDIM + c8] = o;
    }
}

extern "C" void kernel_launch(void* const* d_in, const int* in_sizes, int n_in,
                              void* d_out, int out_size, void* d_ws, size_t ws_size,
                              hipStream_t stream) {
    const float* cnn   = (const float*)d_in[0];
    const float* pts   = (const float*)d_in[1];
    const float* mlp_w = (const float*)d_in[2];
    const float* mlp_b = (const float*)d_in[3];
    const float* rnn_w = (const float*)d_in[4];
    const float* rnn_b = (const float*)d_in[5];
    float* out = (float*)d_out;

    // workspace (footprint identical to round 0):
    // NHa(7232x512 u16) | P(7232x256 f32, overlays old NHb exactly)
    // | Tb(7232x256 u16) | mlpw_b(65536 u16) | rnnw_b(131072 u16) | idx
    // h is updated IN-PLACE in NHa: gemm_rnn2 reads only the right half
    // (msg) and writes only the left half (h'), so no double buffer.
    unsigned short* NHa    = (unsigned short*)d_ws;
    float*          P      = (float*)(NHa + (size_t)PADM * 512);     // 7.4 MB
    unsigned short* Tb     = (unsigned short*)(P + (size_t)PADM * CDIM);
    unsigned short* mlpw_b = Tb + (size_t)PADM * CDIM;
    unsigned short* rnnw_b = mlpw_b + 65536;
    int*            idx    = (int*)(rnnw_b + 131072);

    mega_kernel<<<TKB + IHB + SUB, 512, 0, stream>>>(
        pts, idx, cnn, NHa, out, mlp_w, rnn_w, mlpw_b, rnnw_b);

    for (int it = 0; it < 3; ++it) {
        // D1: Tb = relu(mlp_w.h + mb)  AND  P = Wh.h + rb   (one dispatch)
        gemm_dual<<<904, 256, 0, stream>>>(
            NHa, mlpw_b, mlp_b, rnnw_b, rnn_b, Tb, P);
        // D2: msg = mean_k Tb[idx] -> NHa right half
        gather_mean<<<M_REAL / 4, 256, 0, stream>>>(Tb, idx, NHa);
        // D3: h' = relu(Wm.msg + P)
        if (it < 2) {
            gemm_rnn2<<<452, 256, 0, stream>>>(
                NHa, rnnw_b, P, NHa, nullptr, 0);
        } else {
            gemm_rnn2<<<452, 256, 0, stream>>>(
                NHa, rnnw_b, P, nullptr, out, 1);
        }
    }
}